// Round 11
// baseline (253.255 us; speedup 1.0000x reference)
//
#include <hip/hip_runtime.h>

#define N_NODES 100000
#define N_EDGES 1600000
#define IN_C 32
#define HID_C 64
#define OUT_C 32

#define EPB 1024                                 // edges per hist/place block
#define NBLK ((N_EDGES + EPB - 1) / EPB)         // 1563
#define BSH 8                                    // 256 nodes per bucket
#define BKN (1 << BSH)
#define NB ((N_NODES + BKN - 1) / BKN)           // 391

typedef __attribute__((ext_vector_type(8))) short bf16x8;
typedef __attribute__((ext_vector_type(8))) unsigned short u16x8;
typedef __attribute__((ext_vector_type(4))) float f32x4;

__device__ __forceinline__ unsigned short f2bf(float f) {
    unsigned u = __float_as_uint(f);
    return (unsigned short)((u + 0x7fffu + ((u >> 16) & 1u)) >> 16);
}
__device__ __forceinline__ float bf2f(unsigned short h) {
    return __uint_as_float((unsigned)h << 16);
}

// ---- pass A: bucket histogram (LDS only) + fused x->bf16 cast -----------
__global__ __launch_bounds__(256) void bucket_hist_kernel(
    const int* __restrict__ dst, int* __restrict__ gh,
    const float* __restrict__ x, ushort* __restrict__ xb) {
    // fused cast: one thread per 8 floats (grid exactly covers 400K items)
    int ci = blockIdx.x * 256 + threadIdx.x;
    if (ci < N_NODES * IN_C / 8) {
        const float4* p = (const float4*)&x[(size_t)ci * 8];
        float4 a = p[0], b = p[1];
        u16x8 o;
        o[0] = f2bf(a.x); o[1] = f2bf(a.y); o[2] = f2bf(a.z); o[3] = f2bf(a.w);
        o[4] = f2bf(b.x); o[5] = f2bf(b.y); o[6] = f2bf(b.z); o[7] = f2bf(b.w);
        *(u16x8*)&xb[(size_t)ci * 8] = o;
    }

    __shared__ int lh[NB];
    for (int i = threadIdx.x; i < NB; i += 256) lh[i] = 0;
    __syncthreads();
    int base = blockIdx.x * EPB;
#pragma unroll
    for (int j = 0; j < EPB / 256; ++j) {
        int e = base + j * 256 + threadIdx.x;
        if (e < N_EDGES) atomicAdd(&lh[dst[e] >> BSH], 1);
    }
    __syncthreads();
    for (int i = threadIdx.x; i < NB; i += 256)
        gh[i * NBLK + blockIdx.x] = lh[i];
}

__global__ void cast_w_kernel(const float* __restrict__ w1l,
                              const float* __restrict__ w1r,
                              const float* __restrict__ w2l,
                              const float* __restrict__ w2r,
                              ushort* __restrict__ wb) {
    for (int i = threadIdx.x; i < 8192; i += 256) {
        float v;
        if (i < 2048) v = w1l[i];
        else if (i < 4096) v = w1r[i - 2048];
        else if (i < 6144) v = w2l[i - 4096];
        else v = w2r[i - 6144];
        wb[i] = f2bf(v);
    }
}

// ---- pass B: per-bucket exclusive scan of gh across blocks + totals -----
__global__ __launch_bounds__(256) void bucket_scan_kernel(
    int* __restrict__ gh, int* __restrict__ btot) {
    int b = blockIdx.x;
    int t = threadIdx.x;
    __shared__ int ssum[256];
    int v[7];
    int base = t * 7;
    int s = 0;
#pragma unroll
    for (int j = 0; j < 7; ++j) {
        int idx = base + j;
        int val = (idx < NBLK) ? gh[b * NBLK + idx] : 0;
        v[j] = s;
        s += val;
    }
    ssum[t] = s;
    __syncthreads();
    for (int o = 1; o < 256; o <<= 1) {
        int val = (t >= o) ? ssum[t - o] : 0;
        __syncthreads();
        ssum[t] += val;
        __syncthreads();
    }
    int texcl = ssum[t] - s;
#pragma unroll
    for (int j = 0; j < 7; ++j) {
        int idx = base + j;
        if (idx < NBLK) gh[b * NBLK + idx] = texcl + v[j];
    }
    if (t == 255) btot[b] = ssum[255];
}

// ---- pass C: scan bucket totals -> bucket bases -------------------------
__global__ void base_scan_kernel(const int* __restrict__ btot,
                                 int* __restrict__ bbase) {
    int acc = 0;
    for (int i = 0; i < NB; ++i) { bbase[i] = acc; acc += btot[i]; }
    bbase[NB] = acc;
}

// ---- pass D: place packed (src<<8 | dst&255) into bucket-sorted tmp -----
__global__ __launch_bounds__(256) void bucket_place_kernel(
    const int* __restrict__ src, const int* __restrict__ dst,
    const int* __restrict__ gh, const int* __restrict__ bbase,
    unsigned* __restrict__ tmp) {
    __shared__ int cur[NB];
    for (int i = threadIdx.x; i < NB; i += 256)
        cur[i] = bbase[i] + gh[i * NBLK + blockIdx.x];
    __syncthreads();
    int base = blockIdx.x * EPB;
#pragma unroll
    for (int j = 0; j < EPB / 256; ++j) {
        int e = base + j * 256 + threadIdx.x;
        if (e < N_EDGES) {
            int d = dst[e];
            int slot = atomicAdd(&cur[d >> BSH], 1);
            tmp[slot] = ((unsigned)src[e] << 8) | (unsigned)(d & (BKN - 1));
        }
    }
}

// ---- pass E: per-bucket counts + rowptr + perm (all LDS) ----------------
__global__ __launch_bounds__(512) void count_place_kernel(
    const unsigned* __restrict__ tmp, const int* __restrict__ bbase,
    int* __restrict__ counts, int* __restrict__ rowptr,
    int* __restrict__ perm) {
    __shared__ int lcnt[BKN];
    __shared__ int sscan[BKN];
    __shared__ int cur[BKN];
    int b = blockIdx.x;
    int tid = threadIdx.x;
    int start = bbase[b], end = bbase[b + 1];
    if (tid < BKN) lcnt[tid] = 0;
    __syncthreads();
    for (int i = start + tid; i < end; i += 512)
        atomicAdd(&lcnt[tmp[i] & (BKN - 1)], 1);
    __syncthreads();
    if (tid < BKN) sscan[tid] = lcnt[tid];
    __syncthreads();
    for (int o = 1; o < BKN; o <<= 1) {
        int v = 0;
        if (tid < BKN && tid >= o) v = sscan[tid - o];
        __syncthreads();
        if (tid < BKN) sscan[tid] += v;
        __syncthreads();
    }
    if (tid < BKN) {
        int excl = sscan[tid] - lcnt[tid] + start;
        cur[tid] = excl;
        int n = (b << BSH) + tid;
        if (n < N_NODES) { rowptr[n] = excl; counts[n] = lcnt[tid]; }
    }
    __syncthreads();
    for (int i = start + tid; i < end; i += 512) {
        unsigned p = tmp[i];
        int slot = atomicAdd(&cur[p & (BKN - 1)], 1);
        perm[slot] = (int)(p >> 8);
    }
}

// ---- gather 1: mean of bf16 rows -> bf16 mean1, channel-split -----------
// Grid = 2*ggrid; first half of blocks handles channels 0..15, second 16..31.
// Working set per phase = 3.2 MB -> fits per-XCD L2 (4 MB) -> random reads
// become L2 hits after warmup. 32 edges in flight per wave (2 lanes/edge).
__global__ __launch_bounds__(256) void gather_mean_kernel(
    const ushort* __restrict__ xb, const int* __restrict__ rowptr,
    const int* __restrict__ counts, const int* __restrict__ perm,
    ushort* __restrict__ mb) {
    int ggrid = (N_NODES + 3) / 4;
    int half = (blockIdx.x >= ggrid) ? 1 : 0;
    int blk = blockIdx.x - half * ggrid;
    int lane = threadIdx.x & 63;
    int wid = threadIdx.x >> 6;
    int n = blk * 4 + wid;
    if (n >= N_NODES) return;
    int g = lane >> 1;          // edge slot 0..31
    int q = lane & 1;           // channel octet within half
    int start = rowptr[n];
    int cnt = counts[n];
    int end = start + cnt;
    float acc[8] = {0, 0, 0, 0, 0, 0, 0, 0};
    for (int i = start + g; i < end; i += 32) {
        int idx = perm[i];
        u16x8 v = *(const u16x8*)&xb[(size_t)idx * 32 + half * 16 + q * 8];
#pragma unroll
        for (int k = 0; k < 8; ++k) acc[k] += bf2f(v[k]);
    }
#pragma unroll
    for (int off = 2; off < 64; off <<= 1)
#pragma unroll
        for (int k = 0; k < 8; ++k) acc[k] += __shfl_xor(acc[k], off, 64);
    if (g == 0) {
        float inv = 1.0f / fmaxf((float)cnt, 1.0f);
        u16x8 o;
#pragma unroll
        for (int k = 0; k < 8; ++k) o[k] = f2bf(acc[k] * inv);
        *(u16x8*)&mb[(size_t)n * 32 + half * 16 + q * 8] = o;
    }
}

// ---- gather 2: mean of bf16 t rows + root term -> out (f32), split -----
__global__ __launch_bounds__(256) void gather_final_kernel(
    const ushort* __restrict__ tb, const int* __restrict__ rowptr,
    const int* __restrict__ counts, const int* __restrict__ perm,
    const float* __restrict__ r, float* __restrict__ out) {
    int ggrid = (N_NODES + 3) / 4;
    int half = (blockIdx.x >= ggrid) ? 1 : 0;
    int blk = blockIdx.x - half * ggrid;
    int lane = threadIdx.x & 63;
    int wid = threadIdx.x >> 6;
    int n = blk * 4 + wid;
    if (n >= N_NODES) return;
    int g = lane >> 1;
    int q = lane & 1;
    int start = rowptr[n];
    int cnt = counts[n];
    int end = start + cnt;
    float acc[8] = {0, 0, 0, 0, 0, 0, 0, 0};
    for (int i = start + g; i < end; i += 32) {
        int idx = perm[i];
        u16x8 v = *(const u16x8*)&tb[(size_t)idx * 32 + half * 16 + q * 8];
#pragma unroll
        for (int k = 0; k < 8; ++k) acc[k] += bf2f(v[k]);
    }
#pragma unroll
    for (int off = 2; off < 64; off <<= 1)
#pragma unroll
        for (int k = 0; k < 8; ++k) acc[k] += __shfl_xor(acc[k], off, 64);
    if (g == 0) {
        float inv = 1.0f / fmaxf((float)cnt, 1.0f);
        size_t o0 = (size_t)n * 32 + half * 16 + q * 8;
        const float4* rp = (const float4*)&r[o0];
        float4 r0 = rp[0], r1 = rp[1];
        float4* op = (float4*)&out[o0];
        op[0] = make_float4(acc[0] * inv + r0.x, acc[1] * inv + r0.y,
                            acc[2] * inv + r0.z, acc[3] * inv + r0.w);
        op[1] = make_float4(acc[4] * inv + r1.x, acc[5] * inv + r1.y,
                            acc[6] * inv + r1.z, acc[7] * inv + r1.w);
    }
}

// ---- MFMA transform: 16 nodes per wave-chunk, 16x16x32 bf16 -------------
__global__ __launch_bounds__(256) void transform_mfma_kernel(
    const ushort* __restrict__ xb, const ushort* __restrict__ mb,
    const ushort* __restrict__ wb, const float* __restrict__ b1,
    const float* __restrict__ b2, ushort* __restrict__ tb,
    float* __restrict__ r) {
    __shared__ ushort hlds[4][16 * 72];    // per-wave h tile, padded stride 72
    int lane = threadIdx.x & 63;
    int wid = threadIdx.x >> 6;
    int l15 = lane & 15, lhi = lane >> 4;

    const ushort* w1l = wb;
    const ushort* w1r = wb + 2048;
    const ushort* w2l = wb + 4096;
    const ushort* w2r = wb + 6144;

    bf16x8 B1l[4], B1r[4];
#pragma unroll
    for (int jt = 0; jt < 4; ++jt) {
        B1l[jt] = *(const bf16x8*)&w1l[(jt * 16 + l15) * 32 + 8 * lhi];
        B1r[jt] = *(const bf16x8*)&w1r[(jt * 16 + l15) * 32 + 8 * lhi];
    }
    bf16x8 B2l[2][2], B2r[2][2];
#pragma unroll
    for (int ct = 0; ct < 2; ++ct)
#pragma unroll
        for (int kc = 0; kc < 2; ++kc) {
            B2l[ct][kc] = *(const bf16x8*)&w2l[(ct * 16 + l15) * 64 + kc * 32 + 8 * lhi];
            B2r[ct][kc] = *(const bf16x8*)&w2r[(ct * 16 + l15) * 64 + kc * 32 + 8 * lhi];
        }
    float bias1[4];
#pragma unroll
    for (int jt = 0; jt < 4; ++jt) bias1[jt] = b1[jt * 16 + l15];
    float bias2[2] = { b2[l15], b2[16 + l15] };

    ushort* hl = hlds[wid];

#pragma unroll
    for (int chunk = 0; chunk < 2; ++chunk) {
        int n0 = blockIdx.x * 128 + wid * 32 + chunk * 16;
        int nrow = n0 + l15;
        bf16x8 Am = {}, Ax = {};
        if (nrow < N_NODES) {
            Am = *(const bf16x8*)&mb[(size_t)nrow * 32 + 8 * lhi];
            Ax = *(const bf16x8*)&xb[(size_t)nrow * 32 + 8 * lhi];
        }
#pragma unroll
        for (int jt = 0; jt < 4; ++jt) {
            f32x4 acc = {};
            acc = __builtin_amdgcn_mfma_f32_16x16x32_bf16(Am, B1l[jt], acc, 0, 0, 0);
            acc = __builtin_amdgcn_mfma_f32_16x16x32_bf16(Ax, B1r[jt], acc, 0, 0, 0);
#pragma unroll
            for (int reg = 0; reg < 4; ++reg) {
                float h = fmaxf(acc[reg] + bias1[jt], 0.0f);
                hl[(lhi * 4 + reg) * 72 + jt * 16 + l15] = f2bf(h);
            }
        }
        bf16x8 Ah0 = *(const bf16x8*)&hl[l15 * 72 + 8 * lhi];
        bf16x8 Ah1 = *(const bf16x8*)&hl[l15 * 72 + 32 + 8 * lhi];
#pragma unroll
        for (int ct = 0; ct < 2; ++ct) {
            f32x4 acc = {};
            acc = __builtin_amdgcn_mfma_f32_16x16x32_bf16(Ah0, B2l[ct][0], acc, 0, 0, 0);
            acc = __builtin_amdgcn_mfma_f32_16x16x32_bf16(Ah1, B2l[ct][1], acc, 0, 0, 0);
#pragma unroll
            for (int reg = 0; reg < 4; ++reg) {
                int nr = n0 + lhi * 4 + reg;
                if (nr < N_NODES)
                    tb[(size_t)nr * 32 + ct * 16 + l15] = f2bf(acc[reg]);
            }
        }
#pragma unroll
        for (int ct = 0; ct < 2; ++ct) {
            f32x4 acc = {};
            acc = __builtin_amdgcn_mfma_f32_16x16x32_bf16(Ah0, B2r[ct][0], acc, 0, 0, 0);
            acc = __builtin_amdgcn_mfma_f32_16x16x32_bf16(Ah1, B2r[ct][1], acc, 0, 0, 0);
#pragma unroll
            for (int reg = 0; reg < 4; ++reg) {
                int nr = n0 + lhi * 4 + reg;
                if (nr < N_NODES)
                    r[(size_t)nr * 32 + ct * 16 + l15] = acc[reg] + bias2[ct];
            }
        }
    }
}

// ---- launch -------------------------------------------------------------

extern "C" void kernel_launch(void* const* d_in, const int* in_sizes, int n_in,
                              void* d_out, int out_size, void* d_ws, size_t ws_size,
                              hipStream_t stream) {
    const float* x   = (const float*)d_in[0];
    const float* W1l = (const float*)d_in[1];
    const float* W1r = (const float*)d_in[2];
    const float* b1  = (const float*)d_in[3];
    const float* W2l = (const float*)d_in[4];
    const float* W2r = (const float*)d_in[5];
    const float* b2  = (const float*)d_in[6];
    const int*   ei  = (const int*)d_in[7];   // [2, N_EDGES]
    const int* src = ei;
    const int* dst = ei + N_EDGES;

    char* ws = (char*)d_ws;
    int*      gh     = (int*)ws;             ws += (size_t)NB * NBLK * 4;
    int*      btot   = (int*)ws;             ws += (size_t)(NB + 8) * 4;
    int*      bbase  = (int*)ws;             ws += (size_t)(NB + 8) * 4;
    int*      counts = (int*)ws;             ws += (size_t)N_NODES * 4;
    int*      rowptr = (int*)ws;             ws += (size_t)N_NODES * 4;
    int*      perm   = (int*)ws;             ws += (size_t)N_EDGES * 4;
    unsigned* tmp    = (unsigned*)ws;        ws += (size_t)N_EDGES * 4;
    // mb (bf16 mean1, 6.4MB) aliases tmp (6.4MB): tmp dead after count_place.
    ushort*   mb     = (ushort*)tmp;
    ushort*   xb     = (ushort*)ws;          ws += (size_t)N_NODES * IN_C * 2;
    ushort*   wb     = (ushort*)ws;          ws += (size_t)8192 * 2;
    ushort*   tb     = (ushort*)ws;          ws += (size_t)N_NODES * OUT_C * 2;
    float*    r      = (float*)ws;           ws += (size_t)N_NODES * OUT_C * 4;

    dim3 blk(256);
    int ggrid = (N_NODES + 3) / 4;

    cast_w_kernel<<<1, blk, 0, stream>>>(W1l, W1r, W2l, W2r, wb);
    bucket_hist_kernel<<<NBLK, blk, 0, stream>>>(dst, gh, x, xb);
    bucket_scan_kernel<<<NB, blk, 0, stream>>>(gh, btot);
    base_scan_kernel<<<1, 1, 0, stream>>>(btot, bbase);
    bucket_place_kernel<<<NBLK, blk, 0, stream>>>(src, dst, gh, bbase, tmp);
    count_place_kernel<<<NB, dim3(512), 0, stream>>>(tmp, bbase, counts, rowptr, perm);

    gather_mean_kernel<<<2 * ggrid, blk, 0, stream>>>(xb, rowptr, counts, perm, mb);
    transform_mfma_kernel<<<(N_NODES + 127) / 128, blk, 0, stream>>>(
        xb, mb, wb, b1, b2, tb, r);
    gather_final_kernel<<<2 * ggrid, blk, 0, stream>>>(tb, rowptr, counts, perm, r,
                                                       (float*)d_out);
}

// Round 12
// 173.491 us; speedup vs baseline: 1.4598x; 1.4598x over previous
//
#include <hip/hip_runtime.h>

#define N_NODES 100000
#define N_EDGES 1600000
#define IN_C 32
#define HID_C 64
#define OUT_C 32

#define EPB 1024                                 // edges per hist/place block
#define NBLK ((N_EDGES + EPB - 1) / EPB)         // 1563
#define BSH 8                                    // 256 nodes per bucket
#define BKN (1 << BSH)
#define NB ((N_NODES + BKN - 1) / BKN)           // 391

typedef __attribute__((ext_vector_type(8))) short bf16x8;
typedef __attribute__((ext_vector_type(8))) unsigned short u16x8;
typedef __attribute__((ext_vector_type(4))) float f32x4;

__device__ __forceinline__ unsigned short f2bf(float f) {
    unsigned u = __float_as_uint(f);
    return (unsigned short)((u + 0x7fffu + ((u >> 16) & 1u)) >> 16);
}
__device__ __forceinline__ float bf2f(unsigned short h) {
    return __uint_as_float((unsigned)h << 16);
}

// ---- pass A: bucket histogram (LDS only) + fused x->bf16 cast -----------
__global__ __launch_bounds__(256) void bucket_hist_kernel(
    const int* __restrict__ dst, int* __restrict__ gh,
    const float* __restrict__ x, ushort* __restrict__ xb) {
    int ci = blockIdx.x * 256 + threadIdx.x;
    if (ci < N_NODES * IN_C / 8) {
        const float4* p = (const float4*)&x[(size_t)ci * 8];
        float4 a = p[0], b = p[1];
        u16x8 o;
        o[0] = f2bf(a.x); o[1] = f2bf(a.y); o[2] = f2bf(a.z); o[3] = f2bf(a.w);
        o[4] = f2bf(b.x); o[5] = f2bf(b.y); o[6] = f2bf(b.z); o[7] = f2bf(b.w);
        *(u16x8*)&xb[(size_t)ci * 8] = o;
    }

    __shared__ int lh[NB];
    for (int i = threadIdx.x; i < NB; i += 256) lh[i] = 0;
    __syncthreads();
    int base = blockIdx.x * EPB;
#pragma unroll
    for (int j = 0; j < EPB / 256; ++j) {
        int e = base + j * 256 + threadIdx.x;
        if (e < N_EDGES) atomicAdd(&lh[dst[e] >> BSH], 1);
    }
    __syncthreads();
    for (int i = threadIdx.x; i < NB; i += 256)
        gh[i * NBLK + blockIdx.x] = lh[i];
}

__global__ void cast_w_kernel(const float* __restrict__ w1l,
                              const float* __restrict__ w1r,
                              const float* __restrict__ w2l,
                              const float* __restrict__ w2r,
                              ushort* __restrict__ wb) {
    for (int i = threadIdx.x; i < 8192; i += 256) {
        float v;
        if (i < 2048) v = w1l[i];
        else if (i < 4096) v = w1r[i - 2048];
        else if (i < 6144) v = w2l[i - 4096];
        else v = w2r[i - 6144];
        wb[i] = f2bf(v);
    }
}

// ---- pass B: per-bucket exclusive scan of gh across blocks + totals -----
__global__ __launch_bounds__(256) void bucket_scan_kernel(
    int* __restrict__ gh, int* __restrict__ btot) {
    int b = blockIdx.x;
    int t = threadIdx.x;
    __shared__ int ssum[256];
    int v[7];
    int base = t * 7;
    int s = 0;
#pragma unroll
    for (int j = 0; j < 7; ++j) {
        int idx = base + j;
        int val = (idx < NBLK) ? gh[b * NBLK + idx] : 0;
        v[j] = s;
        s += val;
    }
    ssum[t] = s;
    __syncthreads();
    for (int o = 1; o < 256; o <<= 1) {
        int val = (t >= o) ? ssum[t - o] : 0;
        __syncthreads();
        ssum[t] += val;
        __syncthreads();
    }
    int texcl = ssum[t] - s;
#pragma unroll
    for (int j = 0; j < 7; ++j) {
        int idx = base + j;
        if (idx < NBLK) gh[b * NBLK + idx] = texcl + v[j];
    }
    if (t == 255) btot[b] = ssum[255];
}

// ---- pass C: scan bucket totals -> bucket bases -------------------------
__global__ void base_scan_kernel(const int* __restrict__ btot,
                                 int* __restrict__ bbase) {
    int acc = 0;
    for (int i = 0; i < NB; ++i) { bbase[i] = acc; acc += btot[i]; }
    bbase[NB] = acc;
}

// ---- pass D: place packed (src<<8 | dst&255) into bucket-sorted tmp -----
__global__ __launch_bounds__(256) void bucket_place_kernel(
    const int* __restrict__ src, const int* __restrict__ dst,
    const int* __restrict__ gh, const int* __restrict__ bbase,
    unsigned* __restrict__ tmp) {
    __shared__ int cur[NB];
    for (int i = threadIdx.x; i < NB; i += 256)
        cur[i] = bbase[i] + gh[i * NBLK + blockIdx.x];
    __syncthreads();
    int base = blockIdx.x * EPB;
#pragma unroll
    for (int j = 0; j < EPB / 256; ++j) {
        int e = base + j * 256 + threadIdx.x;
        if (e < N_EDGES) {
            int d = dst[e];
            int slot = atomicAdd(&cur[d >> BSH], 1);
            tmp[slot] = ((unsigned)src[e] << 8) | (unsigned)(d & (BKN - 1));
        }
    }
}

// ---- pass E: per-bucket counts + rowptr + perm (all LDS) ----------------
__global__ __launch_bounds__(512) void count_place_kernel(
    const unsigned* __restrict__ tmp, const int* __restrict__ bbase,
    int* __restrict__ counts, int* __restrict__ rowptr,
    int* __restrict__ perm) {
    __shared__ int lcnt[BKN];
    __shared__ int sscan[BKN];
    __shared__ int cur[BKN];
    int b = blockIdx.x;
    int tid = threadIdx.x;
    int start = bbase[b], end = bbase[b + 1];
    if (tid < BKN) lcnt[tid] = 0;
    __syncthreads();
    for (int i = start + tid; i < end; i += 512)
        atomicAdd(&lcnt[tmp[i] & (BKN - 1)], 1);
    __syncthreads();
    if (tid < BKN) sscan[tid] = lcnt[tid];
    __syncthreads();
    for (int o = 1; o < BKN; o <<= 1) {
        int v = 0;
        if (tid < BKN && tid >= o) v = sscan[tid - o];
        __syncthreads();
        if (tid < BKN) sscan[tid] += v;
        __syncthreads();
    }
    if (tid < BKN) {
        int excl = sscan[tid] - lcnt[tid] + start;
        cur[tid] = excl;
        int n = (b << BSH) + tid;
        if (n < N_NODES) { rowptr[n] = excl; counts[n] = lcnt[tid]; }
    }
    __syncthreads();
    for (int i = start + tid; i < end; i += 512) {
        unsigned p = tmp[i];
        int slot = atomicAdd(&cur[p & (BKN - 1)], 1);
        perm[slot] = (int)(p >> 8);
    }
}

// ---- gather 1: 4 nodes per wave, batched dependency chain ---------------
// Per wave: 8 independent rowptr/counts loads -> 4 independent perm loads
// -> 4 independent 16-edge feature batches (64 loads in flight). The 3
// latency rounds amortize over 4 nodes (was 1 node -> 45us latency-bound).
__global__ __launch_bounds__(256) void gather_mean_kernel(
    const ushort* __restrict__ xb, const int* __restrict__ rowptr,
    const int* __restrict__ counts, const int* __restrict__ perm,
    ushort* __restrict__ mb) {
    int lane = threadIdx.x & 63;
    int wid = threadIdx.x >> 6;
    int nb = (blockIdx.x * 4 + wid) * 4;
    if (nb >= N_NODES) return;
    int g = lane >> 2;          // edge slot 0..15
    int q = lane & 3;           // channel octet

    int st[4], cn[4];
#pragma unroll
    for (int k = 0; k < 4; ++k) {
        int n = nb + k;
        bool v = n < N_NODES;
        st[k] = v ? rowptr[n] : 0;
        cn[k] = v ? counts[n] : 0;
    }

    int p[4];
#pragma unroll
    for (int k = 0; k < 4; ++k)
        p[k] = (g < cn[k]) ? perm[st[k] + g] : -1;

    float acc[4][8];
#pragma unroll
    for (int k = 0; k < 4; ++k)
#pragma unroll
        for (int j = 0; j < 8; ++j) acc[k][j] = 0.f;

#pragma unroll
    for (int k = 0; k < 4; ++k) {
        if (p[k] >= 0) {
            u16x8 v = *(const u16x8*)&xb[(size_t)p[k] * 32 + q * 8];
#pragma unroll
            for (int j = 0; j < 8; ++j) acc[k][j] += bf2f(v[j]);
        }
    }
    // tails (cnt > 16, rare)
#pragma unroll
    for (int k = 0; k < 4; ++k) {
        for (int i = st[k] + g + 16; i < st[k] + cn[k]; i += 16) {
            int idx = perm[i];
            u16x8 v = *(const u16x8*)&xb[(size_t)idx * 32 + q * 8];
#pragma unroll
            for (int j = 0; j < 8; ++j) acc[k][j] += bf2f(v[j]);
        }
    }

#pragma unroll
    for (int k = 0; k < 4; ++k)
#pragma unroll
        for (int off = 4; off < 64; off <<= 1)
#pragma unroll
            for (int j = 0; j < 8; ++j)
                acc[k][j] += __shfl_xor(acc[k][j], off, 64);

    if (g == 0) {
#pragma unroll
        for (int k = 0; k < 4; ++k) {
            int n = nb + k;
            if (n < N_NODES) {
                float inv = 1.0f / fmaxf((float)cn[k], 1.0f);
                u16x8 o;
#pragma unroll
                for (int j = 0; j < 8; ++j) o[j] = f2bf(acc[k][j] * inv);
                *(u16x8*)&mb[(size_t)n * 32 + q * 8] = o;
            }
        }
    }
}

// ---- gather 2: same structure; adds root term, writes f32 out -----------
__global__ __launch_bounds__(256) void gather_final_kernel(
    const ushort* __restrict__ tb, const int* __restrict__ rowptr,
    const int* __restrict__ counts, const int* __restrict__ perm,
    const float* __restrict__ r, float* __restrict__ out) {
    int lane = threadIdx.x & 63;
    int wid = threadIdx.x >> 6;
    int nb = (blockIdx.x * 4 + wid) * 4;
    if (nb >= N_NODES) return;
    int g = lane >> 2;
    int q = lane & 3;

    int st[4], cn[4];
#pragma unroll
    for (int k = 0; k < 4; ++k) {
        int n = nb + k;
        bool v = n < N_NODES;
        st[k] = v ? rowptr[n] : 0;
        cn[k] = v ? counts[n] : 0;
    }

    int p[4];
#pragma unroll
    for (int k = 0; k < 4; ++k)
        p[k] = (g < cn[k]) ? perm[st[k] + g] : -1;

    float acc[4][8];
#pragma unroll
    for (int k = 0; k < 4; ++k)
#pragma unroll
        for (int j = 0; j < 8; ++j) acc[k][j] = 0.f;

#pragma unroll
    for (int k = 0; k < 4; ++k) {
        if (p[k] >= 0) {
            u16x8 v = *(const u16x8*)&tb[(size_t)p[k] * 32 + q * 8];
#pragma unroll
            for (int j = 0; j < 8; ++j) acc[k][j] += bf2f(v[j]);
        }
    }
#pragma unroll
    for (int k = 0; k < 4; ++k) {
        for (int i = st[k] + g + 16; i < st[k] + cn[k]; i += 16) {
            int idx = perm[i];
            u16x8 v = *(const u16x8*)&tb[(size_t)idx * 32 + q * 8];
#pragma unroll
            for (int j = 0; j < 8; ++j) acc[k][j] += bf2f(v[j]);
        }
    }

#pragma unroll
    for (int k = 0; k < 4; ++k)
#pragma unroll
        for (int off = 4; off < 64; off <<= 1)
#pragma unroll
            for (int j = 0; j < 8; ++j)
                acc[k][j] += __shfl_xor(acc[k][j], off, 64);

    if (g == 0) {
#pragma unroll
        for (int k = 0; k < 4; ++k) {
            int n = nb + k;
            if (n < N_NODES) {
                float inv = 1.0f / fmaxf((float)cn[k], 1.0f);
                size_t o0 = (size_t)n * 32 + q * 8;
                const float4* rp = (const float4*)&r[o0];
                float4 r0 = rp[0], r1 = rp[1];
                float4* op = (float4*)&out[o0];
                op[0] = make_float4(acc[k][0] * inv + r0.x, acc[k][1] * inv + r0.y,
                                    acc[k][2] * inv + r0.z, acc[k][3] * inv + r0.w);
                op[1] = make_float4(acc[k][4] * inv + r1.x, acc[k][5] * inv + r1.y,
                                    acc[k][6] * inv + r1.z, acc[k][7] * inv + r1.w);
            }
        }
    }
}

// ---- MFMA transform: 16 nodes per wave-chunk, 16x16x32 bf16 -------------
__global__ __launch_bounds__(256) void transform_mfma_kernel(
    const ushort* __restrict__ xb, const ushort* __restrict__ mb,
    const ushort* __restrict__ wb, const float* __restrict__ b1,
    const float* __restrict__ b2, ushort* __restrict__ tb,
    float* __restrict__ r) {
    __shared__ ushort hlds[4][16 * 72];
    int lane = threadIdx.x & 63;
    int wid = threadIdx.x >> 6;
    int l15 = lane & 15, lhi = lane >> 4;

    const ushort* w1l = wb;
    const ushort* w1r = wb + 2048;
    const ushort* w2l = wb + 4096;
    const ushort* w2r = wb + 6144;

    bf16x8 B1l[4], B1r[4];
#pragma unroll
    for (int jt = 0; jt < 4; ++jt) {
        B1l[jt] = *(const bf16x8*)&w1l[(jt * 16 + l15) * 32 + 8 * lhi];
        B1r[jt] = *(const bf16x8*)&w1r[(jt * 16 + l15) * 32 + 8 * lhi];
    }
    bf16x8 B2l[2][2], B2r[2][2];
#pragma unroll
    for (int ct = 0; ct < 2; ++ct)
#pragma unroll
        for (int kc = 0; kc < 2; ++kc) {
            B2l[ct][kc] = *(const bf16x8*)&w2l[(ct * 16 + l15) * 64 + kc * 32 + 8 * lhi];
            B2r[ct][kc] = *(const bf16x8*)&w2r[(ct * 16 + l15) * 64 + kc * 32 + 8 * lhi];
        }
    float bias1[4];
#pragma unroll
    for (int jt = 0; jt < 4; ++jt) bias1[jt] = b1[jt * 16 + l15];
    float bias2[2] = { b2[l15], b2[16 + l15] };

    ushort* hl = hlds[wid];

#pragma unroll
    for (int chunk = 0; chunk < 2; ++chunk) {
        int n0 = blockIdx.x * 128 + wid * 32 + chunk * 16;
        int nrow = n0 + l15;
        bf16x8 Am = {}, Ax = {};
        if (nrow < N_NODES) {
            Am = *(const bf16x8*)&mb[(size_t)nrow * 32 + 8 * lhi];
            Ax = *(const bf16x8*)&xb[(size_t)nrow * 32 + 8 * lhi];
        }
#pragma unroll
        for (int jt = 0; jt < 4; ++jt) {
            f32x4 acc = {};
            acc = __builtin_amdgcn_mfma_f32_16x16x32_bf16(Am, B1l[jt], acc, 0, 0, 0);
            acc = __builtin_amdgcn_mfma_f32_16x16x32_bf16(Ax, B1r[jt], acc, 0, 0, 0);
#pragma unroll
            for (int reg = 0; reg < 4; ++reg) {
                float h = fmaxf(acc[reg] + bias1[jt], 0.0f);
                hl[(lhi * 4 + reg) * 72 + jt * 16 + l15] = f2bf(h);
            }
        }
        bf16x8 Ah0 = *(const bf16x8*)&hl[l15 * 72 + 8 * lhi];
        bf16x8 Ah1 = *(const bf16x8*)&hl[l15 * 72 + 32 + 8 * lhi];
#pragma unroll
        for (int ct = 0; ct < 2; ++ct) {
            f32x4 acc = {};
            acc = __builtin_amdgcn_mfma_f32_16x16x32_bf16(Ah0, B2l[ct][0], acc, 0, 0, 0);
            acc = __builtin_amdgcn_mfma_f32_16x16x32_bf16(Ah1, B2l[ct][1], acc, 0, 0, 0);
#pragma unroll
            for (int reg = 0; reg < 4; ++reg) {
                int nr = n0 + lhi * 4 + reg;
                if (nr < N_NODES)
                    tb[(size_t)nr * 32 + ct * 16 + l15] = f2bf(acc[reg]);
            }
        }
#pragma unroll
        for (int ct = 0; ct < 2; ++ct) {
            f32x4 acc = {};
            acc = __builtin_amdgcn_mfma_f32_16x16x32_bf16(Ah0, B2r[ct][0], acc, 0, 0, 0);
            acc = __builtin_amdgcn_mfma_f32_16x16x32_bf16(Ah1, B2r[ct][1], acc, 0, 0, 0);
#pragma unroll
            for (int reg = 0; reg < 4; ++reg) {
                int nr = n0 + lhi * 4 + reg;
                if (nr < N_NODES)
                    r[(size_t)nr * 32 + ct * 16 + l15] = acc[reg] + bias2[ct];
            }
        }
    }
}

// ---- launch -------------------------------------------------------------

extern "C" void kernel_launch(void* const* d_in, const int* in_sizes, int n_in,
                              void* d_out, int out_size, void* d_ws, size_t ws_size,
                              hipStream_t stream) {
    const float* x   = (const float*)d_in[0];
    const float* W1l = (const float*)d_in[1];
    const float* W1r = (const float*)d_in[2];
    const float* b1  = (const float*)d_in[3];
    const float* W2l = (const float*)d_in[4];
    const float* W2r = (const float*)d_in[5];
    const float* b2  = (const float*)d_in[6];
    const int*   ei  = (const int*)d_in[7];   // [2, N_EDGES]
    const int* src = ei;
    const int* dst = ei + N_EDGES;

    char* ws = (char*)d_ws;
    int*      gh     = (int*)ws;             ws += (size_t)NB * NBLK * 4;
    int*      btot   = (int*)ws;             ws += (size_t)(NB + 8) * 4;
    int*      bbase  = (int*)ws;             ws += (size_t)(NB + 8) * 4;
    int*      counts = (int*)ws;             ws += (size_t)N_NODES * 4;
    int*      rowptr = (int*)ws;             ws += (size_t)N_NODES * 4;
    int*      perm   = (int*)ws;             ws += (size_t)N_EDGES * 4;
    unsigned* tmp    = (unsigned*)ws;        ws += (size_t)N_EDGES * 4;
    // mb (bf16 mean1, 6.4MB) aliases tmp (6.4MB): tmp dead after count_place.
    ushort*   mb     = (ushort*)tmp;
    ushort*   xb     = (ushort*)ws;          ws += (size_t)N_NODES * IN_C * 2;
    ushort*   wb     = (ushort*)ws;          ws += (size_t)8192 * 2;
    ushort*   tb     = (ushort*)ws;          ws += (size_t)N_NODES * OUT_C * 2;
    float*    r      = (float*)ws;           ws += (size_t)N_NODES * OUT_C * 4;

    dim3 blk(256);
    int ggrid = (N_NODES + 15) / 16;   // 4 waves/block x 4 nodes/wave

    cast_w_kernel<<<1, blk, 0, stream>>>(W1l, W1r, W2l, W2r, wb);
    bucket_hist_kernel<<<NBLK, blk, 0, stream>>>(dst, gh, x, xb);
    bucket_scan_kernel<<<NB, blk, 0, stream>>>(gh, btot);
    base_scan_kernel<<<1, 1, 0, stream>>>(btot, bbase);
    bucket_place_kernel<<<NBLK, blk, 0, stream>>>(src, dst, gh, bbase, tmp);
    count_place_kernel<<<NB, dim3(512), 0, stream>>>(tmp, bbase, counts, rowptr, perm);

    gather_mean_kernel<<<ggrid, blk, 0, stream>>>(xb, rowptr, counts, perm, mb);
    transform_mfma_kernel<<<(N_NODES + 127) / 128, blk, 0, stream>>>(
        xb, mb, wb, b1, b2, tb, r);
    gather_final_kernel<<<ggrid, blk, 0, stream>>>(tb, rowptr, counts, perm, r,
                                                   (float*)d_out);
}